// Round 4
// baseline (883.969 us; speedup 1.0000x reference)
//
#include <hip/hip_runtime.h>
#include <hip/hip_bf16.h>
#include <math.h>

// Problem constants
#define D_ 1024
#define F_ 4096
#define E_ 8
#define NTOK 4096          // B*S
#define MAXPAD 9216        // 8192 pairs + 8 experts * 127 padding, rounded up to 128
#define MAXTILES 72        // MAXPAD / 128

// Workspace layout (bytes)
#define OFF_TOPK_IDX 1024
#define OFF_TOPK_W   (OFF_TOPK_IDX + NTOK*2*4)
#define OFF_PTOK     (OFF_TOPK_W + NTOK*2*4)
#define OFF_PW       (OFF_PTOK + MAXPAD*4)
#define OFF_UP       (OFF_PW + MAXPAD*4)
#define OFF_XB       (1u << 20)                      // x bf16: 8 MiB
#define OFF_W1T      (OFF_XB + 8388608u)             // w1^T bf16 [E][F][D]: 64 MiB
#define OFF_W2T      (OFF_W1T + 67108864u)           // w2^T bf16 [E][D][F]: 64 MiB
#define OFF_H        (OFF_W2T + 67108864u)           // h bf16, 1 MiB per 128-row tile

typedef __attribute__((ext_vector_type(8))) short s16x8;
typedef __attribute__((ext_vector_type(4))) float f32x4;

static __device__ inline short f2bf(float f) {
    __hip_bfloat16 h = __float2bfloat16(f);
    return *reinterpret_cast<short*>(&h);
}

// ---------------------------------------------------------------- init
__global__ __launch_bounds__(256) void k0_init(float* out, int* hdr, int* ptok) {
    size_t gid = (size_t)blockIdx.x * 256 + threadIdx.x;
    float4* o4 = (float4*)out;
    const size_t n4 = (size_t)NTOK * D_ / 4;
    for (size_t i = gid; i < n4; i += (size_t)gridDim.x * 256)
        o4[i] = make_float4(0.f, 0.f, 0.f, 0.f);
    if (gid < 16) hdr[gid] = 0;
    for (size_t i = gid; i < MAXPAD; i += (size_t)gridDim.x * 256)
        ptok[i] = -1;
}

// ---------------------------------------------------------------- cast x -> bf16
__global__ __launch_bounds__(256) void kc_x(const float* __restrict__ x, short* __restrict__ xb) {
    size_t i = ((size_t)blockIdx.x * 256 + threadIdx.x) * 8;   // 4M elems / 8
    float4 a = *(const float4*)(x + i);
    float4 b = *(const float4*)(x + i + 4);
    s16x8 o;
    o[0]=f2bf(a.x); o[1]=f2bf(a.y); o[2]=f2bf(a.z); o[3]=f2bf(a.w);
    o[4]=f2bf(b.x); o[5]=f2bf(b.y); o[6]=f2bf(b.z); o[7]=f2bf(b.w);
    *(s16x8*)(xb + i) = o;
}

// ---------------------------------------------------------------- transpose+cast w [e][K][N] -> [e][N][K] bf16
__global__ __launch_bounds__(256) void kc_wT(const float* __restrict__ src,
                                             short* __restrict__ dst, int K, int N) {
    __shared__ float t[64][65];
    int e = blockIdx.z;
    int n0 = blockIdx.x * 64, k0 = blockIdx.y * 64;
    const float* s = src + (size_t)e * K * N;
    short* d = dst + (size_t)e * K * N;
    int tid = threadIdx.x;
    int kr = tid >> 2, cseg = (tid & 3) * 16;      // load: row k, 16 cols
    const float* srow = s + (size_t)(k0 + kr) * N + n0 + cseg;
#pragma unroll
    for (int q = 0; q < 4; q++) {
        float4 v = *(const float4*)(srow + q * 4);
        t[kr][cseg + q*4 + 0] = v.x; t[kr][cseg + q*4 + 1] = v.y;
        t[kr][cseg + q*4 + 2] = v.z; t[kr][cseg + q*4 + 3] = v.w;
    }
    __syncthreads();
    int nr = tid >> 2, kseg = (tid & 3) * 16;      // store: row n, 16 ks
    short* drow = d + (size_t)(n0 + nr) * K + k0 + kseg;
#pragma unroll
    for (int h = 0; h < 2; h++) {
        s16x8 o;
#pragma unroll
        for (int j = 0; j < 8; j++) o[j] = f2bf(t[kseg + h*8 + j][nr]);
        *(s16x8*)(drow + h * 8) = o;
    }
}

// ---------------------------------------------------------------- gating (fp32 exact)
__global__ __launch_bounds__(256) void k1_gate(
    const float* __restrict__ x, const float* __restrict__ gw,
    const float* __restrict__ gb, int* hdr,
    int* __restrict__ topk_idx, float* __restrict__ topk_w,
    float* __restrict__ usage_partial)
{
    int tid  = threadIdx.x;
    int lane = tid & 63;
    int t    = blockIdx.x * 4 + (tid >> 6);
    const float* xr = x + (size_t)t * D_;
    float acc[E_] = {};
    for (int j = 0; j < D_ / 64; j++) {
        int d = j * 64 + lane;
        float xv = xr[d];
        const float4* g4 = (const float4*)(gw + (size_t)d * E_);
        float4 ga = g4[0], gb2 = g4[1];
        acc[0] += xv * ga.x;  acc[1] += xv * ga.y;
        acc[2] += xv * ga.z;  acc[3] += xv * ga.w;
        acc[4] += xv * gb2.x; acc[5] += xv * gb2.y;
        acc[6] += xv * gb2.z; acc[7] += xv * gb2.w;
    }
    for (int e = 0; e < E_; e++) {
        float v = acc[e];
        for (int m = 32; m >= 1; m >>= 1) v += __shfl_xor(v, m, 64);
        acc[e] = v + gb[e];
    }
    if (lane == 0) {
        int i0 = 0; float m0 = acc[0];
        for (int e = 1; e < E_; e++) if (acc[e] > m0) { m0 = acc[e]; i0 = e; }
        int i1 = -1; float m1 = -1e30f;
        for (int e = 0; e < E_; e++) if (e != i0 && acc[e] > m1) { m1 = acc[e]; i1 = e; }
        float e1 = expf(m1 - m0);
        float inv = 1.0f / (1.0f + e1);
        topk_idx[t * 2 + 0] = i0;  topk_idx[t * 2 + 1] = i1;
        topk_w  [t * 2 + 0] = inv; topk_w  [t * 2 + 1] = e1 * inv;
        atomicAdd(&hdr[i0], 1);
        atomicAdd(&hdr[i1], 1);
        float s = 0.f, p[E_];
        for (int e = 0; e < E_; e++) { p[e] = expf(acc[e] - m0); s += p[e]; }
        float invs = 1.0f / s;
        for (int e = 0; e < E_; e++) usage_partial[(size_t)t * E_ + e] = p[e] * invs;
    }
}

// ---------------------------------------------------------------- meta (1 block)
__global__ __launch_bounds__(256) void k2_meta(int* hdr,
    const float* __restrict__ usage_partial, float* out)
{
    __shared__ float red[256];
    int tid = threadIdx.x;
    int e = tid & 7, chunk = tid >> 3;
    float a = 0.f;
    for (int r = chunk; r < NTOK; r += 32) a += usage_partial[(size_t)r * E_ + e];
    red[tid] = a;
    __syncthreads();
    if (tid < 8) {
        float s = 0.f;
        for (int c = 0; c < 32; c++) s += red[c * 8 + tid];
        red[tid] = s;
    }
    __syncthreads();
    if (tid == 0) {
        float aux = 0.f;
        for (int e2 = 0; e2 < E_; e2++) { float u = red[e2] / NTOK; aux += u * u; }
        out[(size_t)NTOK * D_] = (float)E_ * aux;
        int off = 0;
        hdr[16] = 0;
        for (int e2 = 0; e2 < E_; e2++) {
            off += (hdr[e2] + 127) & ~127;
            hdr[16 + e2 + 1] = off;
        }
        int ntiles = off >> 7;
        for (int e2 = 0; e2 < E_; e2++)
            for (int t2 = hdr[16 + e2] >> 7; t2 < hdr[16 + e2 + 1] >> 7; t2++)
                hdr[32 + t2] = e2;
        for (int t2 = ntiles; t2 < MAXTILES; t2++) hdr[32 + t2] = -1;
    }
}

// ---------------------------------------------------------------- scatter
__global__ __launch_bounds__(256) void k3_scatter(int* hdr,
    const int* __restrict__ topk_idx, const float* __restrict__ topk_w,
    int* __restrict__ ptok, float* __restrict__ pw)
{
    int t = blockIdx.x * 256 + threadIdx.x;
    for (int k = 0; k < 2; k++) {
        int e = topk_idx[t * 2 + k];
        float w = topk_w[t * 2 + k];
        int pos = hdr[16 + e] + atomicAdd(&hdr[8 + e], 1);
        ptok[pos] = t;
        pw[pos]   = w;
    }
}

// ---------------------------------------------------------------- GEMM1: h = gelu(x@w1+b1), bf16 MFMA
// 128x128 tile, BK=64, 4 waves (2x2), mfma_f32_16x16x32_bf16.
__global__ __launch_bounds__(256) void k4_gemm1(
    const short* __restrict__ xb, const short* __restrict__ w1t,
    const float* __restrict__ b1, const int* __restrict__ hdr,
    const int* __restrict__ ptok, short* __restrict__ h, int tile_base)
{
    int mtile = tile_base + blockIdx.x;
    int e = hdr[32 + mtile];
    if (e < 0) return;
    const int n0 = blockIdx.y * 128;

    __shared__ __align__(16) char lds[33280];
    char* As = lds;            // [128 rows][8 slots of 16B], slot XOR-swizzled
    char* Bs = lds + 16384;

    int tid = threadIdx.x;
    int w = tid >> 6, lane = tid & 63;
    int wr = w >> 1, wc = w & 1;
    int lg = lane >> 4, lr = lane & 15;

    // staging assignments: chunk q = p*256+tid -> row q>>3, 16B-slot q&7
    const short* asrc[4]; const short* bsrc[4];
    int adst[4], bdst[4];
#pragma unroll
    for (int p = 0; p < 4; p++) {
        int q = p * 256 + tid;
        int r = q >> 3, kb = q & 7;
        int tok = ptok[mtile * 128 + r];
        asrc[p] = (tok >= 0) ? xb + (size_t)tok * D_ + kb * 8 : nullptr;
        bsrc[p] = w1t + ((size_t)e * F_ + n0 + r) * D_ + kb * 8;
        adst[p] = r * 128 + ((kb ^ (r & 7)) * 16);
        bdst[p] = adst[p];
    }

    f32x4 acc[4][4];
#pragma unroll
    for (int i = 0; i < 4; i++)
#pragma unroll
        for (int j = 0; j < 4; j++) acc[i][j] = (f32x4){0.f, 0.f, 0.f, 0.f};

    for (int kt = 0; kt < D_ / 64; kt++) {
        __syncthreads();
#pragma unroll
        for (int p = 0; p < 4; p++) {
            int4 av = asrc[p] ? *(const int4*)(asrc[p] + kt * 64) : make_int4(0,0,0,0);
            *(int4*)(As + adst[p]) = av;
            *(int4*)(Bs + bdst[p]) = *(const int4*)(bsrc[p] + kt * 64);
        }
        __syncthreads();
#pragma unroll
        for (int kh = 0; kh < 2; kh++) {
            s16x8 af[4], bf[4];
#pragma unroll
            for (int mf = 0; mf < 4; mf++) {
                int r = wr * 64 + mf * 16 + lr;
                int slot = (kh * 4 + lg) ^ (r & 7);
                af[mf] = *(const s16x8*)(As + r * 128 + slot * 16);
            }
#pragma unroll
            for (int nf = 0; nf < 4; nf++) {
                int r = wc * 64 + nf * 16 + lr;
                int slot = (kh * 4 + lg) ^ (r & 7);
                bf[nf] = *(const s16x8*)(Bs + r * 128 + slot * 16);
            }
#pragma unroll
            for (int mf = 0; mf < 4; mf++)
#pragma unroll
                for (int nf = 0; nf < 4; nf++)
                    acc[mf][nf] = __builtin_amdgcn_mfma_f32_16x16x32_bf16(
                        af[mf], bf[nf], acc[mf][nf], 0, 0, 0);
        }
    }

    // epilogue via LDS transpose (two 64-col halves), bias+gelu, bf16 h store
    float* epi = (float*)lds;   // [128][65] f32
    const float* b1e = b1 + (size_t)e * F_ + n0;
#pragma unroll
    for (int hb = 0; hb < 2; hb++) {
        __syncthreads();
        if (wc == hb) {
#pragma unroll
            for (int mf = 0; mf < 4; mf++)
#pragma unroll
                for (int nf = 0; nf < 4; nf++)
#pragma unroll
                    for (int reg = 0; reg < 4; reg++) {
                        int row = wr * 64 + mf * 16 + lg * 4 + reg;
                        int col = nf * 16 + lr;
                        epi[row * 65 + col] = acc[mf][nf][reg];
                    }
        }
        __syncthreads();
        int m = tid >> 1, c0 = (tid & 1) * 32;
        short* hrow = h + ((size_t)blockIdx.x * 128 + m) * F_ + n0 + hb * 64 + c0;
        const float* bb = b1e + hb * 64 + c0;
#pragma unroll
        for (int q = 0; q < 4; q++) {
            s16x8 o;
#pragma unroll
            for (int j = 0; j < 8; j++) {
                float v = epi[m * 65 + c0 + q * 8 + j] + bb[q * 8 + j];
                o[j] = f2bf(0.5f * v * (1.0f + erff(v * 0.70710678118654752f)));
            }
            *(s16x8*)(hrow + q * 8) = o;
        }
    }
}

// ---------------------------------------------------------------- GEMM2: out += w*(h@w2+b2), bf16 MFMA
__global__ __launch_bounds__(256) void k5_gemm2(
    const short* __restrict__ h, const short* __restrict__ w2t,
    const float* __restrict__ b2, const int* __restrict__ hdr,
    const int* __restrict__ ptok, const float* __restrict__ pw,
    float* __restrict__ out, int tile_base)
{
    int mtile = tile_base + blockIdx.x;
    int e = hdr[32 + mtile];
    if (e < 0) return;
    const int n0 = blockIdx.y * 128;

    __shared__ __align__(16) char lds[32768];
    char* As = lds;
    char* Bs = lds + 16384;

    int tid = threadIdx.x;
    int w = tid >> 6, lane = tid & 63;
    int wr = w >> 1, wc = w & 1;
    int lg = lane >> 4, lr = lane & 15;

    const short* asrc[4]; const short* bsrc[4];
    int adst[4];
#pragma unroll
    for (int p = 0; p < 4; p++) {
        int q = p * 256 + tid;
        int r = q >> 3, kb = q & 7;
        asrc[p] = h + ((size_t)blockIdx.x * 128 + r) * F_ + kb * 8;
        bsrc[p] = w2t + ((size_t)e * D_ + n0 + r) * F_ + kb * 8;
        adst[p] = r * 128 + ((kb ^ (r & 7)) * 16);
    }

    f32x4 acc[4][4];
#pragma unroll
    for (int i = 0; i < 4; i++)
#pragma unroll
        for (int j = 0; j < 4; j++) acc[i][j] = (f32x4){0.f, 0.f, 0.f, 0.f};

    for (int kt = 0; kt < F_ / 64; kt++) {
        __syncthreads();
#pragma unroll
        for (int p = 0; p < 4; p++) {
            *(int4*)(As + adst[p]) = *(const int4*)(asrc[p] + kt * 64);
            *(int4*)(Bs + adst[p]) = *(const int4*)(bsrc[p] + kt * 64);
        }
        __syncthreads();
#pragma unroll
        for (int kh = 0; kh < 2; kh++) {
            s16x8 af[4], bf[4];
#pragma unroll
            for (int mf = 0; mf < 4; mf++) {
                int r = wr * 64 + mf * 16 + lr;
                int slot = (kh * 4 + lg) ^ (r & 7);
                af[mf] = *(const s16x8*)(As + r * 128 + slot * 16);
            }
#pragma unroll
            for (int nf = 0; nf < 4; nf++) {
                int r = wc * 64 + nf * 16 + lr;
                int slot = (kh * 4 + lg) ^ (r & 7);
                bf[nf] = *(const s16x8*)(Bs + r * 128 + slot * 16);
            }
#pragma unroll
            for (int mf = 0; mf < 4; mf++)
#pragma unroll
                for (int nf = 0; nf < 4; nf++)
                    acc[mf][nf] = __builtin_amdgcn_mfma_f32_16x16x32_bf16(
                        af[mf], bf[nf], acc[mf][nf], 0, 0, 0);
        }
    }

    // epilogue: weighted atomic scatter (2 adds per out element total)
    float bias[4];
#pragma unroll
    for (int nf = 0; nf < 4; nf++)
        bias[nf] = b2[(size_t)e * D_ + n0 + wc * 64 + nf * 16 + lr];
#pragma unroll
    for (int mf = 0; mf < 4; mf++)
#pragma unroll
        for (int reg = 0; reg < 4; reg++) {
            int m = wr * 64 + mf * 16 + lg * 4 + reg;
            int tok = ptok[mtile * 128 + m];
            if (tok < 0) continue;
            float wgt = pw[mtile * 128 + m];
            float* orow = out + (size_t)tok * D_ + n0 + wc * 64;
#pragma unroll
            for (int nf = 0; nf < 4; nf++)
                unsafeAtomicAdd(orow + nf * 16 + lr, (acc[mf][nf][reg] + bias[nf]) * wgt);
        }
}

// ---------------------------------------------------------------- host
extern "C" void kernel_launch(void* const* d_in, const int* in_sizes, int n_in,
                              void* d_out, int out_size, void* d_ws, size_t ws_size,
                              hipStream_t stream)
{
    const float* x  = (const float*)d_in[0];
    const float* gw = (const float*)d_in[1];
    const float* gb = (const float*)d_in[2];
    const float* w1 = (const float*)d_in[3];
    const float* b1 = (const float*)d_in[4];
    const float* w2 = (const float*)d_in[5];
    const float* b2 = (const float*)d_in[6];
    float* out = (float*)d_out;

    char* ws = (char*)d_ws;
    int*   hdr      = (int*)ws;
    int*   topk_idx = (int*)(ws + OFF_TOPK_IDX);
    float* topk_w   = (float*)(ws + OFF_TOPK_W);
    int*   ptok     = (int*)(ws + OFF_PTOK);
    float* pw       = (float*)(ws + OFF_PW);
    float* up       = (float*)(ws + OFF_UP);
    short* xb       = (short*)(ws + OFF_XB);
    short* w1t      = (short*)(ws + OFF_W1T);
    short* w2t      = (short*)(ws + OFF_W2T);
    short* h        = (short*)(ws + OFF_H);

    if (ws_size < (size_t)OFF_H + (1u << 20)) return;   // ws too small: fail loudly

    size_t cap = (ws_size - OFF_H) >> 20;               // 1 MiB per 128-row tile
    if (cap > MAXTILES) cap = MAXTILES;

    hipLaunchKernelGGL(k0_init, dim3(1024), dim3(256), 0, stream, out, hdr, ptok);
    hipLaunchKernelGGL(kc_x,    dim3((NTOK*D_)/(256*8)), dim3(256), 0, stream, x, xb);
    hipLaunchKernelGGL(kc_wT,   dim3(F_/64, D_/64, E_), dim3(256), 0, stream, w1, w1t, D_, F_);
    hipLaunchKernelGGL(kc_wT,   dim3(D_/64, F_/64, E_), dim3(256), 0, stream, w2, w2t, F_, D_);
    hipLaunchKernelGGL(k1_gate, dim3(NTOK / 4), dim3(256), 0, stream, x, gw, gb, hdr, topk_idx, topk_w, up);
    hipLaunchKernelGGL(k2_meta, dim3(1), dim3(256), 0, stream, hdr, up, out);
    hipLaunchKernelGGL(k3_scatter, dim3(NTOK/256), dim3(256), 0, stream, hdr, topk_idx, topk_w, ptok, pw);
    for (int base = 0; base < MAXTILES; base += (int)cap) {
        int nt = MAXTILES - base < (int)cap ? MAXTILES - base : (int)cap;
        hipLaunchKernelGGL(k4_gemm1, dim3(nt, F_ / 128), dim3(256), 0, stream,
                           xb, w1t, b1, hdr, ptok, h, base);
        hipLaunchKernelGGL(k5_gemm2, dim3(nt, D_ / 128), dim3(256), 0, stream,
                           h, w2t, b2, hdr, ptok, pw, out, base);
    }
}

// Round 6
// 823.610 us; speedup vs baseline: 1.0733x; 1.0733x over previous
//
#include <hip/hip_runtime.h>
#include <hip/hip_bf16.h>
#include <math.h>

// Problem constants
#define D_ 1024
#define F_ 4096
#define E_ 8
#define NTOK 4096          // B*S
#define MAXPAD 9216        // 8192 pairs + 8 experts * 127 padding, rounded up to 128
#define MAXTILES 72        // MAXPAD / 128

// Workspace layout (bytes)
#define OFF_TOPK_IDX 1024
#define OFF_TOPK_W   (OFF_TOPK_IDX + NTOK*2*4)
#define OFF_PTOK     (OFF_TOPK_W + NTOK*2*4)
#define OFF_PW       (OFF_PTOK + MAXPAD*4)
#define OFF_UP       (OFF_PW + MAXPAD*4)
#define OFF_XB       (1u << 20)                      // x bf16: 8 MiB
#define OFF_W1T      (OFF_XB + 8388608u)             // w1^T bf16 [E][F][D]: 64 MiB
#define OFF_W2T      (OFF_W1T + 67108864u)           // w2^T bf16 [E][D][F]: 64 MiB
#define OFF_H        (OFF_W2T + 67108864u)           // h bf16, 1 MiB per 128-row tile

typedef __attribute__((ext_vector_type(8))) short s16x8;
typedef __attribute__((ext_vector_type(4))) float f32x4;

static __device__ inline short f2bf(float f) {
    __hip_bfloat16 h = __float2bfloat16(f);
    return *reinterpret_cast<short*>(&h);
}

// async 16B global->LDS (dest = wave-uniform base + lane*16; source per-lane)
#define GLOAD16(g, l) __builtin_amdgcn_global_load_lds( \
    (const __attribute__((address_space(1))) void*)(g), \
    (__attribute__((address_space(3))) void*)(l), 16, 0, 0)

// ---------------------------------------------------------------- init + cast x
__global__ __launch_bounds__(256) void kA_init(const float* __restrict__ x,
    short* __restrict__ xb, float* out, int* hdr, int* ptok)
{
    int gid = blockIdx.x * 256 + threadIdx.x;          // 0..524287
    float4 z4 = make_float4(0.f, 0.f, 0.f, 0.f);
    float4* o4 = (float4*)out;
    o4[gid] = z4;
    o4[gid + 524288] = z4;
    size_t i = (size_t)gid * 8;
    float4 a = *(const float4*)(x + i);
    float4 b = *(const float4*)(x + i + 4);
    s16x8 o;
    o[0]=f2bf(a.x); o[1]=f2bf(a.y); o[2]=f2bf(a.z); o[3]=f2bf(a.w);
    o[4]=f2bf(b.x); o[5]=f2bf(b.y); o[6]=f2bf(b.z); o[7]=f2bf(b.w);
    *(s16x8*)(xb + i) = o;
    if (gid < 16) hdr[gid] = 0;
    if (gid < MAXPAD) ptok[gid] = -1;
}

// ---------------------------------------------------------------- transpose+cast both weights
// [e][K][N] -> [e][N][K] bf16; y<8 -> w1 expert y; y>=8 -> w2 expert y-8
__global__ __launch_bounds__(256) void kB_wT(
    const float* __restrict__ w1, const float* __restrict__ w2,
    short* __restrict__ w1t, short* __restrict__ w2t)
{
    __shared__ float t[64][65];
    int z = blockIdx.y;
    const float* s; short* d; int K, N, nb, kb2;
    if (z < 8) { s = w1 + (size_t)z * D_ * F_;  d = w1t + (size_t)z * D_ * F_;
                 K = D_; N = F_; nb = blockIdx.x & 63; kb2 = blockIdx.x >> 6; }
    else       { s = w2 + (size_t)(z-8) * F_ * D_; d = w2t + (size_t)(z-8) * F_ * D_;
                 K = F_; N = D_; nb = blockIdx.x & 15; kb2 = blockIdx.x >> 4; }
    int n0 = nb * 64, k0 = kb2 * 64;
    int tid = threadIdx.x;
    int kr = tid >> 2, cseg = (tid & 3) * 16;
    const float* srow = s + (size_t)(k0 + kr) * N + n0 + cseg;
#pragma unroll
    for (int q = 0; q < 4; q++) {
        float4 v = *(const float4*)(srow + q * 4);
        t[kr][cseg + q*4 + 0] = v.x; t[kr][cseg + q*4 + 1] = v.y;
        t[kr][cseg + q*4 + 2] = v.z; t[kr][cseg + q*4 + 3] = v.w;
    }
    __syncthreads();
    int nr = tid >> 2, kseg = (tid & 3) * 16;
    short* drow = d + (size_t)(n0 + nr) * K + k0 + kseg;
#pragma unroll
    for (int h = 0; h < 2; h++) {
        s16x8 o;
#pragma unroll
        for (int j = 0; j < 8; j++) o[j] = f2bf(t[kseg + h*8 + j][nr]);
        *(s16x8*)(drow + h * 8) = o;
    }
}

// ---------------------------------------------------------------- gating (fp32 exact)
__global__ __launch_bounds__(256) void k1_gate(
    const float* __restrict__ x, const float* __restrict__ gw,
    const float* __restrict__ gb, int* hdr,
    int* __restrict__ topk_idx, float* __restrict__ topk_w,
    float* __restrict__ usage_partial)
{
    int tid  = threadIdx.x;
    int lane = tid & 63;
    int t    = blockIdx.x * 4 + (tid >> 6);
    const float* xr = x + (size_t)t * D_;
    float acc[E_] = {};
    for (int j = 0; j < D_ / 64; j++) {
        int d = j * 64 + lane;
        float xv = xr[d];
        const float4* g4 = (const float4*)(gw + (size_t)d * E_);
        float4 ga = g4[0], gb2 = g4[1];
        acc[0] += xv * ga.x;  acc[1] += xv * ga.y;
        acc[2] += xv * ga.z;  acc[3] += xv * ga.w;
        acc[4] += xv * gb2.x; acc[5] += xv * gb2.y;
        acc[6] += xv * gb2.z; acc[7] += xv * gb2.w;
    }
    for (int e = 0; e < E_; e++) {
        float v = acc[e];
        for (int m = 32; m >= 1; m >>= 1) v += __shfl_xor(v, m, 64);
        acc[e] = v + gb[e];
    }
    if (lane == 0) {
        int i0 = 0; float m0 = acc[0];
        for (int e = 1; e < E_; e++) if (acc[e] > m0) { m0 = acc[e]; i0 = e; }
        int i1 = -1; float m1 = -1e30f;
        for (int e = 0; e < E_; e++) if (e != i0 && acc[e] > m1) { m1 = acc[e]; i1 = e; }
        float e1 = expf(m1 - m0);
        float inv = 1.0f / (1.0f + e1);
        topk_idx[t * 2 + 0] = i0;  topk_idx[t * 2 + 1] = i1;
        topk_w  [t * 2 + 0] = inv; topk_w  [t * 2 + 1] = e1 * inv;
        atomicAdd(&hdr[i0], 1);
        atomicAdd(&hdr[i1], 1);
        float s = 0.f, p[E_];
        for (int e = 0; e < E_; e++) { p[e] = expf(acc[e] - m0); s += p[e]; }
        float invs = 1.0f / s;
        for (int e = 0; e < E_; e++) usage_partial[(size_t)t * E_ + e] = p[e] * invs;
    }
}

// ---------------------------------------------------------------- meta + scatter (1 block)
__global__ __launch_bounds__(256) void kC_meta(int* hdr,
    const float* __restrict__ usage_partial,
    const int* __restrict__ topk_idx, const float* __restrict__ topk_w,
    int* __restrict__ ptok, float* __restrict__ pw, float* out)
{
    __shared__ float red[256];
    __shared__ int cur[8];
    int tid = threadIdx.x;
    int e = tid & 7, chunk = tid >> 3;
    float a = 0.f;
    for (int r = chunk; r < NTOK; r += 32) a += usage_partial[(size_t)r * E_ + e];
    red[tid] = a;
    __syncthreads();
    if (tid < 8) {
        float s = 0.f;
        for (int c = 0; c < 32; c++) s += red[c * 8 + tid];
        red[tid] = s;
    }
    __syncthreads();
    if (tid == 0) {
        float aux = 0.f;
        for (int e2 = 0; e2 < E_; e2++) { float u = red[e2] / NTOK; aux += u * u; }
        out[(size_t)NTOK * D_] = (float)E_ * aux;
        int off = 0;
        hdr[16] = 0;
        for (int e2 = 0; e2 < E_; e2++) {
            off += (hdr[e2] + 127) & ~127;
            hdr[16 + e2 + 1] = off;
        }
        int ntiles = off >> 7;
        for (int e2 = 0; e2 < E_; e2++)
            for (int t2 = hdr[16 + e2] >> 7; t2 < hdr[16 + e2 + 1] >> 7; t2++)
                hdr[32 + t2] = e2;
        for (int t2 = ntiles; t2 < MAXTILES; t2++) hdr[32 + t2] = -1;
    }
    __syncthreads();
    if (tid < 8) cur[tid] = hdr[16 + tid];
    __syncthreads();
    for (int t = tid; t < NTOK; t += 256) {
#pragma unroll
        for (int k = 0; k < 2; k++) {
            int e2 = topk_idx[t * 2 + k];
            int pos = atomicAdd(&cur[e2], 1);
            ptok[pos] = t;
            pw[pos]   = topk_w[t * 2 + k];
        }
    }
}

// ---------------------------------------------------------------- GEMM1: h = gelu(x@w1+b1)
// 128x128 tile, BK=64, 4 waves, mfma_f32_16x16x32_bf16, global_load_lds staging.
__global__ __launch_bounds__(256) void k4_gemm1(
    const short* __restrict__ xb, const short* __restrict__ w1t,
    const float* __restrict__ b1, const int* __restrict__ hdr,
    const int* __restrict__ ptok, short* __restrict__ h, int tile_base, int nt)
{
    // XCD-aware 2D chunk: 288 blocks/XCD = 36 mtiles x 8 n-blocks (y fastest)
    int flat = blockIdx.x;
    int ltile, yb;
    if (nt == 72) {
        int xcd = flat & 7, local = flat >> 3;
        ltile = (xcd & 1) * 36 + (local >> 3);
        yb    = ((xcd >> 1) << 3) + (local & 7);
    } else { ltile = flat >> 5; yb = flat & 31; }
    int mtile = tile_base + ltile;
    int e = hdr[32 + mtile];
    if (e < 0) return;
    const int n0 = yb * 128;

    __shared__ __align__(16) char lds[33280];
    char* As = lds;            // linear [128 rows][8 slots of 16B]; data slot-XOR'd via source
    char* Bs = lds + 16384;

    int tid = threadIdx.x;
    int wid = tid >> 6, lane = tid & 63;
    int wr = wid >> 1, wc = wid & 1;
    int lg = lane >> 4, lr = lane & 15;

    // per-lane pre-swizzled global sources; chunk q = p*256+tid -> row q>>3, slot q&7
    const short* ag[4]; const short* bg[4];
#pragma unroll
    for (int p = 0; p < 4; p++) {
        int q = p * 256 + tid;
        int r = q >> 3, kb = q & 7;
        int kbs = kb ^ (r & 7);
        int tok = ptok[mtile * 128 + r];
        if (tok < 0) tok = 0;   // padded row: load token0 (finite, discarded later)
        ag[p] = xb + (size_t)tok * D_ + kbs * 8;
        bg[p] = w1t + ((size_t)e * F_ + n0 + r) * D_ + kbs * 8;
    }

    f32x4 acc[4][4];
#pragma unroll
    for (int i = 0; i < 4; i++)
#pragma unroll
        for (int j = 0; j < 4; j++) acc[i][j] = (f32x4){0.f, 0.f, 0.f, 0.f};

    for (int kt = 0; kt < D_ / 64; kt++) {
        __syncthreads();
#pragma unroll
        for (int p = 0; p < 4; p++) {
            GLOAD16(ag[p] + kt * 64, As + p * 4096 + wid * 1024);
            GLOAD16(bg[p] + kt * 64, Bs + p * 4096 + wid * 1024);
        }
        __syncthreads();   // compiler drains vmcnt before barrier
#pragma unroll
        for (int kh = 0; kh < 2; kh++) {
            s16x8 af[4], bf[4];
#pragma unroll
            for (int mf = 0; mf < 4; mf++) {
                int r = wr * 64 + mf * 16 + lr;
                int slot = (kh * 4 + lg) ^ (r & 7);
                af[mf] = *(const s16x8*)(As + r * 128 + slot * 16);
            }
#pragma unroll
            for (int nf = 0; nf < 4; nf++) {
                int r = wc * 64 + nf * 16 + lr;
                int slot = (kh * 4 + lg) ^ (r & 7);
                bf[nf] = *(const s16x8*)(Bs + r * 128 + slot * 16);
            }
#pragma unroll
            for (int mf = 0; mf < 4; mf++)
#pragma unroll
                for (int nf = 0; nf < 4; nf++)
                    acc[mf][nf] = __builtin_amdgcn_mfma_f32_16x16x32_bf16(
                        af[mf], bf[nf], acc[mf][nf], 0, 0, 0);
        }
    }

    // epilogue via LDS transpose, bias + exact gelu, bf16 h store
    float* epi = (float*)lds;   // [128][65] f32
    const float* b1e = b1 + (size_t)e * F_ + n0;
#pragma unroll
    for (int hb = 0; hb < 2; hb++) {
        __syncthreads();
        if (wc == hb) {
#pragma unroll
            for (int mf = 0; mf < 4; mf++)
#pragma unroll
                for (int nf = 0; nf < 4; nf++)
#pragma unroll
                    for (int reg = 0; reg < 4; reg++) {
                        int row = wr * 64 + mf * 16 + lg * 4 + reg;
                        int col = nf * 16 + lr;
                        epi[row * 65 + col] = acc[mf][nf][reg];
                    }
        }
        __syncthreads();
        int m = tid >> 1, c0 = (tid & 1) * 32;
        short* hrow = h + ((size_t)ltile * 128 + m) * F_ + n0 + hb * 64 + c0;
        const float* bb = b1e + hb * 64 + c0;
#pragma unroll
        for (int q = 0; q < 4; q++) {
            s16x8 o;
#pragma unroll
            for (int j = 0; j < 8; j++) {
                float v = epi[m * 65 + c0 + q * 8 + j] + bb[q * 8 + j];
                o[j] = f2bf(0.5f * v * (1.0f + erff(v * 0.70710678118654752f)));
            }
            *(s16x8*)(hrow + q * 8) = o;
        }
    }
}

// ---------------------------------------------------------------- GEMM2: out += w*(h@w2+b2), split-K=2
__global__ __launch_bounds__(256) void k5_gemm2(
    const short* __restrict__ h, const short* __restrict__ w2t,
    const float* __restrict__ b2, const int* __restrict__ hdr,
    const int* __restrict__ ptok, const float* __restrict__ pw,
    float* __restrict__ out, int tile_base, int nt)
{
    // XCD-aware chunk: 144 blocks/XCD = 18 mtiles x 8 n-blocks, kslice fixed per XCD
    int flat = blockIdx.x;
    int ltile, yb, z;
    if (nt == 72) {
        int xcd = flat & 7, local = flat >> 3;
        z     = xcd >> 2;
        ltile = (xcd & 3) * 18 + (local >> 3);
        yb    = local & 7;
    } else {
        yb = flat & 7; int t2 = flat >> 3;
        ltile = t2 % nt; z = t2 / nt;
    }
    int mtile = tile_base + ltile;
    int e = hdr[32 + mtile];
    if (e < 0) return;
    const int n0 = yb * 128;

    __shared__ __align__(16) char lds[32768];
    char* As = lds;
    char* Bs = lds + 16384;

    int tid = threadIdx.x;
    int wid = tid >> 6, lane = tid & 63;
    int wr = wid >> 1, wc = wid & 1;
    int lg = lane >> 4, lr = lane & 15;

    const short* ag[4]; const short* bg[4];
#pragma unroll
    for (int p = 0; p < 4; p++) {
        int q = p * 256 + tid;
        int r = q >> 3, kb = q & 7;
        int kbs = kb ^ (r & 7);
        ag[p] = h + ((size_t)ltile * 128 + r) * F_ + z * 2048 + kbs * 8;
        bg[p] = w2t + ((size_t)e * D_ + n0 + r) * F_ + z * 2048 + kbs * 8;
    }

    f32x4 acc[4][4];
#pragma unroll
    for (int i = 0; i < 4; i++)
#pragma unroll
        for (int j = 0; j < 4; j++) acc[i][j] = (f32x4){0.f, 0.f, 0.f, 0.f};

    for (int kt = 0; kt < 32; kt++) {
        __syncthreads();
#pragma unroll
        for (int p = 0; p < 4; p++) {
            GLOAD16(ag[p] + kt * 64, As + p * 4096 + wid * 1024);
            GLOAD16(bg[p] + kt * 64, Bs + p * 4096 + wid * 1024);
        }
        __syncthreads();
#pragma unroll
        for (int kh = 0; kh < 2; kh++) {
            s16x8 af[4], bf[4];
#pragma unroll
            for (int mf = 0; mf < 4; mf++) {
                int r = wr * 64 + mf * 16 + lr;
                int slot = (kh * 4 + lg) ^ (r & 7);
                af[mf] = *(const s16x8*)(As + r * 128 + slot * 16);
            }
#pragma unroll
            for (int nf = 0; nf < 4; nf++) {
                int r = wc * 64 + nf * 16 + lr;
                int slot = (kh * 4 + lg) ^ (r & 7);
                bf[nf] = *(const s16x8*)(Bs + r * 128 + slot * 16);
            }
#pragma unroll
            for (int mf = 0; mf < 4; mf++)
#pragma unroll
                for (int nf = 0; nf < 4; nf++)
                    acc[mf][nf] = __builtin_amdgcn_mfma_f32_16x16x32_bf16(
                        af[mf], bf[nf], acc[mf][nf], 0, 0, 0);
        }
    }

    // epilogue: weighted atomic scatter; bias added by kslice 0 only
    float bias[4];
#pragma unroll
    for (int nf = 0; nf < 4; nf++)
        bias[nf] = (z == 0) ? b2[(size_t)e * D_ + n0 + wc * 64 + nf * 16 + lr] : 0.f;
#pragma unroll
    for (int mf = 0; mf < 4; mf++)
#pragma unroll
        for (int reg = 0; reg < 4; reg++) {
            int m = wr * 64 + mf * 16 + lg * 4 + reg;
            int tok = ptok[mtile * 128 + m];
            if (tok < 0) continue;
            float wgt = pw[mtile * 128 + m];
            float* orow = out + (size_t)tok * D_ + n0 + wc * 64;
#pragma unroll
            for (int nf = 0; nf < 4; nf++)
                unsafeAtomicAdd(orow + nf * 16 + lr, (acc[mf][nf][reg] + bias[nf]) * wgt);
        }
}

// ---------------------------------------------------------------- host
extern "C" void kernel_launch(void* const* d_in, const int* in_sizes, int n_in,
                              void* d_out, int out_size, void* d_ws, size_t ws_size,
                              hipStream_t stream)
{
    const float* x  = (const float*)d_in[0];
    const float* gw = (const float*)d_in[1];
    const float* gb = (const float*)d_in[2];
    const float* w1 = (const float*)d_in[3];
    const float* b1 = (const float*)d_in[4];
    const float* w2 = (const float*)d_in[5];
    const float* b2 = (const float*)d_in[6];
    float* out = (float*)d_out;

    char* ws = (char*)d_ws;
    int*   hdr      = (int*)ws;
    int*   topk_idx = (int*)(ws + OFF_TOPK_IDX);
    float* topk_w   = (float*)(ws + OFF_TOPK_W);
    int*   ptok     = (int*)(ws + OFF_PTOK);
    float* pw       = (float*)(ws + OFF_PW);
    float* up       = (float*)(ws + OFF_UP);
    short* xb       = (short*)(ws + OFF_XB);
    short* w1t      = (short*)(ws + OFF_W1T);
    short* w2t      = (short*)(ws + OFF_W2T);
    short* h        = (short*)(ws + OFF_H);

    if (ws_size < (size_t)OFF_H + (1u << 20)) return;

    size_t cap = (ws_size - OFF_H) >> 20;               // 1 MiB per 128-row tile
    if (cap > MAXTILES) cap = MAXTILES;

    hipLaunchKernelGGL(kA_init, dim3(2048), dim3(256), 0, stream, x, xb, out, hdr, ptok);
    hipLaunchKernelGGL(kB_wT,   dim3(1024, 16), dim3(256), 0, stream, w1, w2, w1t, w2t);
    hipLaunchKernelGGL(k1_gate, dim3(NTOK / 4), dim3(256), 0, stream, x, gw, gb, hdr, topk_idx, topk_w, up);
    hipLaunchKernelGGL(kC_meta, dim3(1), dim3(256), 0, stream, hdr, up, topk_idx, topk_w, ptok, pw, out);
    for (int base = 0; base < MAXTILES; base += (int)cap) {
        int nt = MAXTILES - base < (int)cap ? MAXTILES - base : (int)cap;
        hipLaunchKernelGGL(k4_gemm1, dim3(nt * 32), dim3(256), 0, stream,
                           xb, w1t, b1, hdr, ptok, h, base, nt);
        hipLaunchKernelGGL(k5_gemm2, dim3(nt * 16), dim3(256), 0, stream,
                           h, w2t, b2, hdr, ptok, pw, out, base, nt);
    }
}

// Round 10
// 606.125 us; speedup vs baseline: 1.4584x; 1.3588x over previous
//
#include <hip/hip_runtime.h>
#include <hip/hip_bf16.h>
#include <math.h>

// Problem constants
#define D_ 1024
#define F_ 4096
#define E_ 8
#define NTOK 4096          // B*S
#define MAXPAD 9216
#define MAXTILES 72        // MAXPAD / 128

// Workspace layout (bytes)
#define OFF_TOPK_IDX 1024
#define OFF_TOPK_W   (OFF_TOPK_IDX + NTOK*2*4)
#define OFF_PTOK     (OFF_TOPK_W + NTOK*2*4)
#define OFF_PW       (OFF_PTOK + MAXPAD*4)
#define OFF_UP       (OFF_PW + MAXPAD*4)
#define OFF_XB       (1u << 20)                      // x bf16: 8 MiB
#define OFF_W1T      (OFF_XB + 8388608u)             // w1^T bf16 [E][F][D]: 64 MiB
#define OFF_W2T      (OFF_W1T + 67108864u)           // w2^T bf16 [E][D][F]: 64 MiB
#define OFF_H        (OFF_W2T + 67108864u)           // h bf16, 1 MiB per 128-row tile

typedef __attribute__((ext_vector_type(8))) short s16x8;
typedef __attribute__((ext_vector_type(4))) float f32x4;

static __device__ inline short f2bf(float f) {
    __hip_bfloat16 h = __float2bfloat16(f);
    return *reinterpret_cast<short*>(&h);
}

// exact-accuracy cheap gelu: erf via Abramowitz-Stegun 7.1.26 (|err|<=1.5e-7)
static __device__ inline float fast_gelu(float x) {
    float y  = x * 0.70710678118654752f;
    float ay = fabsf(y);
    float t  = 1.0f / fmaf(0.3275911f, ay, 1.0f);
    float p  = t * fmaf(t, fmaf(t, fmaf(t, fmaf(t, 1.061405429f, -1.453152027f),
                                        1.421413741f), -0.284496736f), 0.254829592f);
    float e  = __expf(-ay * ay);
    float erfa = fmaf(-p, e, 1.0f);                 // erf(|y|)
    float erfy = __builtin_copysignf(erfa, y);
    return 0.5f * x * (1.0f + erfy);
}

// async 16B global->LDS (dest = wave-uniform base + lane*16; source per-lane)
#define GLOAD16(g, l) __builtin_amdgcn_global_load_lds( \
    (const __attribute__((address_space(1))) void*)(g), \
    (__attribute__((address_space(3))) void*)(l), 16, 0, 0)

// ---------------------------------------------------------------- merged prep:
// blocks [0,16384): weight transpose+cast; [16384,18432): zero out + cast x;
// [18432,19456): gating (fp32 exact, no hdr atomics)
__global__ __launch_bounds__(256) void kM_prep(
    const float* __restrict__ x,  const float* __restrict__ gw,
    const float* __restrict__ gb, const float* __restrict__ w1,
    const float* __restrict__ w2, short* __restrict__ xb,
    short* __restrict__ w1t, short* __restrict__ w2t, float* out,
    int* __restrict__ topk_idx, float* __restrict__ topk_w,
    float* __restrict__ usage_partial)
{
    __shared__ float t[64][65];
    int b = blockIdx.x;
    int tid = threadIdx.x;
    if (b < 16384) {
        // ---- weight transpose+cast [e][K][N] -> [e][N][K]
        int z = b >> 10, flat = b & 1023;
        const float* s; short* d; int K, N, nb, kb2;
        if (z < 8) { s = w1 + (size_t)z * D_ * F_;  d = w1t + (size_t)z * D_ * F_;
                     K = D_; N = F_; nb = flat & 63; kb2 = flat >> 6; }
        else       { s = w2 + (size_t)(z-8) * F_ * D_; d = w2t + (size_t)(z-8) * F_ * D_;
                     K = F_; N = D_; nb = flat & 15; kb2 = flat >> 4; }
        int n0 = nb * 64, k0 = kb2 * 64;
        int kr = tid >> 2, cseg = (tid & 3) * 16;
        const float* srow = s + (size_t)(k0 + kr) * N + n0 + cseg;
#pragma unroll
        for (int q = 0; q < 4; q++) {
            float4 v = *(const float4*)(srow + q * 4);
            t[kr][cseg + q*4 + 0] = v.x; t[kr][cseg + q*4 + 1] = v.y;
            t[kr][cseg + q*4 + 2] = v.z; t[kr][cseg + q*4 + 3] = v.w;
        }
        __syncthreads();
        int nr = tid >> 2, kseg = (tid & 3) * 16;
        short* drow = d + (size_t)(n0 + nr) * K + k0 + kseg;
#pragma unroll
        for (int hh = 0; hh < 2; hh++) {
            s16x8 o;
#pragma unroll
            for (int j = 0; j < 8; j++) o[j] = f2bf(t[kseg + hh*8 + j][nr]);
            *(s16x8*)(drow + hh * 8) = o;
        }
    } else if (b < 18432) {
        // ---- zero out + cast x -> bf16
        int gid = (b - 16384) * 256 + tid;             // 0..524287
        float4 z4 = make_float4(0.f, 0.f, 0.f, 0.f);
        float4* o4 = (float4*)out;
        o4[gid] = z4;
        o4[gid + 524288] = z4;
        size_t i = (size_t)gid * 8;
        float4 a = *(const float4*)(x + i);
        float4 bb = *(const float4*)(x + i + 4);
        s16x8 o;
        o[0]=f2bf(a.x); o[1]=f2bf(a.y); o[2]=f2bf(a.z); o[3]=f2bf(a.w);
        o[4]=f2bf(bb.x); o[5]=f2bf(bb.y); o[6]=f2bf(bb.z); o[7]=f2bf(bb.w);
        *(s16x8*)(xb + i) = o;
    } else {
        // ---- gating: one wave per token
        int lane = tid & 63;
        int tok = (b - 18432) * 4 + (tid >> 6);
        const float* xr = x + (size_t)tok * D_;
        float acc[E_] = {};
        for (int j = 0; j < D_ / 64; j++) {
            int d = j * 64 + lane;
            float xv = xr[d];
            const float4* g4 = (const float4*)(gw + (size_t)d * E_);
            float4 ga = g4[0], gb2 = g4[1];
            acc[0] += xv * ga.x;  acc[1] += xv * ga.y;
            acc[2] += xv * ga.z;  acc[3] += xv * ga.w;
            acc[4] += xv * gb2.x; acc[5] += xv * gb2.y;
            acc[6] += xv * gb2.z; acc[7] += xv * gb2.w;
        }
        for (int e = 0; e < E_; e++) {
            float v = acc[e];
            for (int m = 32; m >= 1; m >>= 1) v += __shfl_xor(v, m, 64);
            acc[e] = v + gb[e];
        }
        if (lane == 0) {
            int i0 = 0; float m0 = acc[0];
            for (int e = 1; e < E_; e++) if (acc[e] > m0) { m0 = acc[e]; i0 = e; }
            int i1 = -1; float m1 = -1e30f;
            for (int e = 0; e < E_; e++) if (e != i0 && acc[e] > m1) { m1 = acc[e]; i1 = e; }
            float e1 = expf(m1 - m0);
            float inv = 1.0f / (1.0f + e1);
            topk_idx[tok * 2 + 0] = i0;  topk_idx[tok * 2 + 1] = i1;
            topk_w  [tok * 2 + 0] = inv; topk_w  [tok * 2 + 1] = e1 * inv;
            float s = 0.f, p[E_];
            for (int e = 0; e < E_; e++) { p[e] = expf(acc[e] - m0); s += p[e]; }
            float invs = 1.0f / s;
            for (int e = 0; e < E_; e++) usage_partial[(size_t)tok * E_ + e] = p[e] * invs;
        }
    }
}

// ---------------------------------------------------------------- meta: histogram,
// offsets, aux loss, tile map, pad-fill, scatter (1 block)
__global__ __launch_bounds__(256) void kC_meta(int* hdr,
    const float* __restrict__ usage_partial,
    const int* __restrict__ topk_idx, const float* __restrict__ topk_w,
    int* __restrict__ ptok, float* __restrict__ pw, float* out)
{
    __shared__ float red[256];
    __shared__ int cnt[8];
    __shared__ int offs[9];
    __shared__ int cur[8];
    int tid = threadIdx.x;
    int e = tid & 7, chunk = tid >> 3;
    float a = 0.f;
    for (int r = chunk; r < NTOK; r += 32) a += usage_partial[(size_t)r * E_ + e];
    red[tid] = a;
    if (tid < 8) cnt[tid] = 0;
    __syncthreads();
    if (tid < 8) {
        float s = 0.f;
        for (int c = 0; c < 32; c++) s += red[c * 8 + tid];
        red[tid] = s;
    }
    for (int i = tid; i < NTOK * 2; i += 256) atomicAdd(&cnt[topk_idx[i]], 1);
    __syncthreads();
    if (tid == 0) {
        float aux = 0.f;
        for (int e2 = 0; e2 < E_; e2++) { float u = red[e2] / NTOK; aux += u * u; }
        out[(size_t)NTOK * D_] = (float)E_ * aux;
        int off = 0;
        offs[0] = 0;
        for (int e2 = 0; e2 < E_; e2++) {
            off += (cnt[e2] + 127) & ~127;
            offs[e2 + 1] = off;
        }
        int ntiles = off >> 7;
        for (int e2 = 0; e2 < E_; e2++)
            for (int t2 = offs[e2] >> 7; t2 < offs[e2 + 1] >> 7; t2++)
                hdr[32 + t2] = e2;
        for (int t2 = ntiles; t2 < MAXTILES; t2++) hdr[32 + t2] = -1;
    }
    __syncthreads();
    if (tid < 8) cur[tid] = offs[tid];
    __syncthreads();
    // pad-fill: -1 for slots scatter won't write
    for (int i = tid; i < MAXPAD; i += 256) {
        int filled = 0;
#pragma unroll
        for (int e2 = 0; e2 < E_; e2++)
            if (i >= offs[e2] && i < offs[e2] + cnt[e2]) filled = 1;
        if (!filled) ptok[i] = -1;
    }
    // scatter (disjoint from pad slots)
    for (int t = tid; t < NTOK; t += 256) {
#pragma unroll
        for (int k = 0; k < 2; k++) {
            int e2 = topk_idx[t * 2 + k];
            int pos = atomicAdd(&cur[e2], 1);
            ptok[pos] = t;
            pw[pos]   = topk_w[t * 2 + k];
        }
    }
}

// ---------------------------------------------------------------- GEMM1: h = gelu(x@w1+b1)
// 128x128 tile, BK=64, 4 waves, 2-phase dbuf pipeline with counted vmcnt.
__global__ __launch_bounds__(256) void k4_gemm1(
    const short* __restrict__ xb, const short* __restrict__ w1t,
    const float* __restrict__ b1, const int* __restrict__ hdr,
    const int* __restrict__ ptok, short* __restrict__ h, int tile_base, int nt)
{
    int flat = blockIdx.x;
    int ltile, yb;
    if (nt == 72) {
        int xcd = flat & 7, local = flat >> 3;
        ltile = (xcd & 1) * 36 + (local >> 3);
        yb    = ((xcd >> 1) << 3) + (local & 7);
    } else { ltile = flat >> 5; yb = flat & 31; }
    int mtile = tile_base + ltile;
    int e = hdr[32 + mtile];
    if (e < 0) return;
    const int n0 = yb * 128;

    __shared__ __align__(16) char lds[65536];   // A0|B0|A1|B1 16KB each; epi reuses

    int tid = threadIdx.x;
    int wid = tid >> 6, lane = tid & 63;
    int wr = wid >> 1, wc = wid & 1;
    int lg = lane >> 4, lr = lane & 15;

    const short* ag[4]; const short* bg[4];
#pragma unroll
    for (int p = 0; p < 4; p++) {
        int q = p * 256 + tid;
        int r = q >> 3, kb = q & 7;
        int kbs = kb ^ (r & 7);
        int tok = ptok[mtile * 128 + r];
        if (tok < 0) tok = 0;
        ag[p] = xb + (size_t)tok * D_ + kbs * 8;
        bg[p] = w1t + ((size_t)e * F_ + n0 + r) * D_ + kbs * 8;
    }

    f32x4 acc[4][4];
#pragma unroll
    for (int i = 0; i < 4; i++)
#pragma unroll
        for (int j = 0; j < 4; j++) acc[i][j] = (f32x4){0.f, 0.f, 0.f, 0.f};

    // prologue: stage tile 0 into buf0
#pragma unroll
    for (int p = 0; p < 4; p++) {
        GLOAD16(ag[p], lds + p * 4096 + wid * 1024);
        GLOAD16(bg[p], lds + 16384 + p * 4096 + wid * 1024);
    }
    int cur = 0;
    for (int kt = 0; kt < 16; kt++) {
        if (kt + 1 < 16) {
            char* nb = lds + (cur ^ 1) * 32768;
#pragma unroll
            for (int p = 0; p < 4; p++) {
                GLOAD16(ag[p] + (kt + 1) * 64, nb + p * 4096 + wid * 1024);
                GLOAD16(bg[p] + (kt + 1) * 64, nb + 16384 + p * 4096 + wid * 1024);
            }
            asm volatile("s_waitcnt vmcnt(8)" ::: "memory");
        } else {
            asm volatile("s_waitcnt vmcnt(0)" ::: "memory");
        }
        __builtin_amdgcn_sched_barrier(0);
        __builtin_amdgcn_s_barrier();
        const char* Ab = lds + cur * 32768;
        const char* Bb = Ab + 16384;
#pragma unroll
        for (int kh = 0; kh < 2; kh++) {
            s16x8 af[4], bf[4];
#pragma unroll
            for (int mf = 0; mf < 4; mf++) {
                int r = wr * 64 + mf * 16 + lr;
                int slot = (kh * 4 + lg) ^ (r & 7);
                af[mf] = *(const s16x8*)(Ab + r * 128 + slot * 16);
            }
#pragma unroll
            for (int nf = 0; nf < 4; nf++) {
                int r = wc * 64 + nf * 16 + lr;
                int slot = (kh * 4 + lg) ^ (r & 7);
                bf[nf] = *(const s16x8*)(Bb + r * 128 + slot * 16);
            }
#pragma unroll
            for (int mf = 0; mf < 4; mf++)
#pragma unroll
                for (int nf = 0; nf < 4; nf++)
                    acc[mf][nf] = __builtin_amdgcn_mfma_f32_16x16x32_bf16(
                        af[mf], bf[nf], acc[mf][nf], 0, 0, 0);
        }
        __builtin_amdgcn_s_barrier();
        cur ^= 1;
    }
    __syncthreads();

    // epilogue via LDS transpose, bias + gelu, bf16 h store
    float* epi = (float*)lds;   // [128][65] f32
    const float* b1e = b1 + (size_t)e * F_ + n0;
#pragma unroll
    for (int hb = 0; hb < 2; hb++) {
        __syncthreads();
        if (wc == hb) {
#pragma unroll
            for (int mf = 0; mf < 4; mf++)
#pragma unroll
                for (int nf = 0; nf < 4; nf++)
#pragma unroll
                    for (int reg = 0; reg < 4; reg++) {
                        int row = wr * 64 + mf * 16 + lg * 4 + reg;
                        int col = nf * 16 + lr;
                        epi[row * 65 + col] = acc[mf][nf][reg];
                    }
        }
        __syncthreads();
        int m = tid >> 1, c0 = (tid & 1) * 32;
        short* hrow = h + ((size_t)ltile * 128 + m) * F_ + n0 + hb * 64 + c0;
        const float* bb = b1e + hb * 64 + c0;
#pragma unroll
        for (int q = 0; q < 4; q++) {
            s16x8 o;
#pragma unroll
            for (int j = 0; j < 8; j++) {
                float v = epi[m * 65 + c0 + q * 8 + j] + bb[q * 8 + j];
                o[j] = f2bf(fast_gelu(v));
            }
            *(s16x8*)(hrow + q * 8) = o;
        }
    }
}

// ---------------------------------------------------------------- GEMM2: out += w*(h@w2+b2)
// split-K=2, 2-phase dbuf pipeline with counted vmcnt.
__global__ __launch_bounds__(256) void k5_gemm2(
    const short* __restrict__ h, const short* __restrict__ w2t,
    const float* __restrict__ b2, const int* __restrict__ hdr,
    const int* __restrict__ ptok, const float* __restrict__ pw,
    float* __restrict__ out, int tile_base, int nt)
{
    int flat = blockIdx.x;
    int ltile, yb, z;
    if (nt == 72) {
        int xcd = flat & 7, local = flat >> 3;
        z     = xcd >> 2;
        ltile = (xcd & 3) * 18 + (local >> 3);
        yb    = local & 7;
    } else {
        yb = flat & 7; int t2 = flat >> 3;
        ltile = t2 % nt; z = t2 / nt;
    }
    int mtile = tile_base + ltile;
    int e = hdr[32 + mtile];
    if (e < 0) return;
    const int n0 = yb * 128;

    __shared__ __align__(16) char lds[65536];

    int tid = threadIdx.x;
    int wid = tid >> 6, lane = tid & 63;
    int wr = wid >> 1, wc = wid & 1;
    int lg = lane >> 4, lr = lane & 15;

    const short* ag[4]; const short* bg[4];
#pragma unroll
    for (int p = 0; p < 4; p++) {
        int q = p * 256 + tid;
        int r = q >> 3, kb = q & 7;
        int kbs = kb ^ (r & 7);
        ag[p] = h + ((size_t)ltile * 128 + r) * F_ + z * 2048 + kbs * 8;
        bg[p] = w2t + ((size_t)e * D_ + n0 + r) * F_ + z * 2048 + kbs * 8;
    }

    f32x4 acc[4][4];
#pragma unroll
    for (int i = 0; i < 4; i++)
#pragma unroll
        for (int j = 0; j < 4; j++) acc[i][j] = (f32x4){0.f, 0.f, 0.f, 0.f};

#pragma unroll
    for (int p = 0; p < 4; p++) {
        GLOAD16(ag[p], lds + p * 4096 + wid * 1024);
        GLOAD16(bg[p], lds + 16384 + p * 4096 + wid * 1024);
    }
    int cur = 0;
    for (int kt = 0; kt < 32; kt++) {
        if (kt + 1 < 32) {
            char* nb = lds + (cur ^ 1) * 32768;
#pragma unroll
            for (int p = 0; p < 4; p++) {
                GLOAD16(ag[p] + (kt + 1) * 64, nb + p * 4096 + wid * 1024);
                GLOAD16(bg[p] + (kt + 1) * 64, nb + 16384 + p * 4096 + wid * 1024);
            }
            asm volatile("s_waitcnt vmcnt(8)" ::: "memory");
        } else {
            asm volatile("s_waitcnt vmcnt(0)" ::: "memory");
        }
        __builtin_amdgcn_sched_barrier(0);
        __builtin_amdgcn_s_barrier();
        const char* Ab = lds + cur * 32768;
        const char* Bb = Ab + 16384;
#pragma unroll
        for (int kh = 0; kh < 2; kh++) {
            s16x8 af[4], bf[4];
#pragma unroll
            for (int mf = 0; mf < 4; mf++) {
                int r = wr * 64 + mf * 16 + lr;
                int slot = (kh * 4 + lg) ^ (r & 7);
                af[mf] = *(const s16x8*)(Ab + r * 128 + slot * 16);
            }
#pragma unroll
            for (int nf = 0; nf < 4; nf++) {
                int r = wc * 64 + nf * 16 + lr;
                int slot = (kh * 4 + lg) ^ (r & 7);
                bf[nf] = *(const s16x8*)(Bb + r * 128 + slot * 16);
            }
#pragma unroll
            for (int mf = 0; mf < 4; mf++)
#pragma unroll
                for (int nf = 0; nf < 4; nf++)
                    acc[mf][nf] = __builtin_amdgcn_mfma_f32_16x16x32_bf16(
                        af[mf], bf[nf], acc[mf][nf], 0, 0, 0);
        }
        __builtin_amdgcn_s_barrier();
        cur ^= 1;
    }

    // epilogue: weighted atomic scatter; bias added by kslice 0 only
    float bias[4];
#pragma unroll
    for (int nf = 0; nf < 4; nf++)
        bias[nf] = (z == 0) ? b2[(size_t)e * D_ + n0 + wc * 64 + nf * 16 + lr] : 0.f;
#pragma unroll
    for (int mf = 0; mf < 4; mf++)
#pragma unroll
        for (int reg = 0; reg < 4; reg++) {
            int m = wr * 64 + mf * 16 + lg * 4 + reg;
            int tok = ptok[mtile * 128 + m];
            if (tok < 0) continue;
            float wgt = pw[mtile * 128 + m];
            float* orow = out + (size_t)tok * D_ + n0 + wc * 64;
#pragma unroll
            for (int nf = 0; nf < 4; nf++)
                unsafeAtomicAdd(orow + nf * 16 + lr, (acc[mf][nf][reg] + bias[nf]) * wgt);
        }
}

// ---------------------------------------------------------------- host
extern "C" void kernel_launch(void* const* d_in, const int* in_sizes, int n_in,
                              void* d_out, int out_size, void* d_ws, size_t ws_size,
                              hipStream_t stream)
{
    const float* x  = (const float*)d_in[0];
    const float* gw = (const float*)d_in[1];
    const float* gb = (const float*)d_in[2];
    const float* w1 = (const float*)d_in[3];
    const float* b1 = (const float*)d_in[4];
    const float* w2 = (const float*)d_in[5];
    const float* b2 = (const float*)d_in[6];
    float* out = (float*)d_out;

    char* ws = (char*)d_ws;
    int*   hdr      = (int*)ws;
    int*   topk_idx = (int*)(ws + OFF_TOPK_IDX);
    float* topk_w   = (float*)(ws + OFF_TOPK_W);
    int*   ptok     = (int*)(ws + OFF_PTOK);
    float* pw       = (float*)(ws + OFF_PW);
    float* up       = (float*)(ws + OFF_UP);
    short* xb       = (short*)(ws + OFF_XB);
    short* w1t      = (short*)(ws + OFF_W1T);
    short* w2t      = (short*)(ws + OFF_W2T);
    short* h        = (short*)(ws + OFF_H);

    if (ws_size < (size_t)OFF_H + (1u << 20)) return;

    size_t cap = (ws_size - OFF_H) >> 20;
    if (cap > MAXTILES) cap = MAXTILES;

    hipLaunchKernelGGL(kM_prep, dim3(19456), dim3(256), 0, stream,
                       x, gw, gb, w1, w2, xb, w1t, w2t, out, topk_idx, topk_w, up);
    hipLaunchKernelGGL(kC_meta, dim3(1), dim3(256), 0, stream,
                       hdr, up, topk_idx, topk_w, ptok, pw, out);
    for (int base = 0; base < MAXTILES; base += (int)cap) {
        int nt = MAXTILES - base < (int)cap ? MAXTILES - base : (int)cap;
        hipLaunchKernelGGL(k4_gemm1, dim3(nt * 32), dim3(256), 0, stream,
                           xb, w1t, b1, hdr, ptok, h, base, nt);
        hipLaunchKernelGGL(k5_gemm2, dim3(nt * 16), dim3(256), 0, stream,
                           h, w2t, b2, hdr, ptok, pw, out, base, nt);
    }
}